// Round 2
// baseline (1055.409 us; speedup 1.0000x reference)
//
#include <hip/hip_runtime.h>
#include <math.h>

#define L_SEQ 200
#define Q_DIM 128
#define H_DIM 128

// ---------------- kernel 1: qw[b,h] = sum_q query[b,q] * W[q,h] ----------------
// One block of 128 threads per batch row. W (64 KB) is L2-hot across blocks.
__global__ __launch_bounds__(128) void qw_kernel(
    const float* __restrict__ query,   // [B, 128]
    const float* __restrict__ W,       // [128, 128]
    float* __restrict__ qw)            // [B, 128]
{
    const int b = blockIdx.x;
    const int h = threadIdx.x;
    __shared__ float s_q[Q_DIM];
    s_q[h] = query[(size_t)b * Q_DIM + h];
    __syncthreads();
    float acc = 0.f;
    #pragma unroll 8
    for (int q = 0; q < Q_DIM; ++q)
        acc = fmaf(s_q[q], W[q * H_DIM + h], acc);   // coalesced across threads
    qw[(size_t)b * H_DIM + h] = acc;
}

// ---------------- kernel 2: attention pooling, hist read ONCE from HBM --------
// One block of 512 threads (8 waves) per batch row.
// lane32 = t&31 owns h-slice [lane32*4, lane32*4+4)
// lgroup = t>>5 (0..15) owns rows l = i*16+lgroup (i=0..11) and, for lgroup<8,
// the tail row 192+lgroup.  -> 12-13 float4 per thread (~52 VGPRs), no spill.
__global__ __launch_bounds__(512, 4) void attn_pool(
    const float* __restrict__ qw,      // [B, 128]
    const float* __restrict__ hist,    // [B, 200, 128]
    const int*   __restrict__ lens,    // [B]
    float* __restrict__ out)           // [B, 128]
{
    const int b = blockIdx.x;
    const int t = threadIdx.x;
    const int lane32 = t & 31;
    const int lgroup = t >> 5;   // 0..15
    const int wid    = t >> 6;   // 0..7

    __shared__ float s_logits[L_SEQ];
    __shared__ float s_part[16 * H_DIM];   // pass-2 partials (8 KB)
    __shared__ float s_red[8];
    __shared__ float s_scalar[2];

    // qw fragment (L2-hot, tiny)
    const float4 qw4 =
        reinterpret_cast<const float4*>(qw + (size_t)b * H_DIM)[lane32];

    // ---- issue ALL hist loads up front (coalesced 1 KB per wave per i) ----
    const float* hrow = hist + (size_t)b * (L_SEQ * H_DIM);
    const bool tail = (lgroup < 8);
    float4 r[13];
    #pragma unroll
    for (int i = 0; i < 12; ++i)
        r[i] = reinterpret_cast<const float4*>(hrow + (i * 16 + lgroup) * H_DIM)[lane32];
    if (tail)
        r[12] = reinterpret_cast<const float4*>(hrow + (192 + lgroup) * H_DIM)[lane32];

    // ---- pass 1: logits[l] = qw . hist[l,:] ----
    #pragma unroll
    for (int i = 0; i < 12; ++i) {
        float p = qw4.x * r[i].x + qw4.y * r[i].y + qw4.z * r[i].z + qw4.w * r[i].w;
        p += __shfl_down(p, 16, 32);
        p += __shfl_down(p, 8, 32);
        p += __shfl_down(p, 4, 32);
        p += __shfl_down(p, 2, 32);
        p += __shfl_down(p, 1, 32);
        if (lane32 == 0) s_logits[i * 16 + lgroup] = p;
    }
    if (tail) {   // wave-uniform branch (waves 0-3 all true, 4-7 all false)
        float p = qw4.x * r[12].x + qw4.y * r[12].y + qw4.z * r[12].z + qw4.w * r[12].w;
        p += __shfl_down(p, 16, 32);
        p += __shfl_down(p, 8, 32);
        p += __shfl_down(p, 4, 32);
        p += __shfl_down(p, 2, 32);
        p += __shfl_down(p, 1, 32);
        if (lane32 == 0) s_logits[192 + lgroup] = p;
    }
    __syncthreads();

    // ---- mask (faithful: valid prefix -> 1e-9) + softmax over 200 ----
    const int len = lens[b];
    float x = -3.0e38f;
    if (t < L_SEQ) {
        const float v = s_logits[t];
        x = (t < len) ? 1e-9f : v;
    }
    float m = x;
    m = fmaxf(m, __shfl_down(m, 32));
    m = fmaxf(m, __shfl_down(m, 16));
    m = fmaxf(m, __shfl_down(m, 8));
    m = fmaxf(m, __shfl_down(m, 4));
    m = fmaxf(m, __shfl_down(m, 2));
    m = fmaxf(m, __shfl_down(m, 1));
    if ((t & 63) == 0) s_red[wid] = m;
    __syncthreads();
    if (t == 0) {
        float g = s_red[0];
        #pragma unroll
        for (int i = 1; i < 8; ++i) g = fmaxf(g, s_red[i]);
        s_scalar[0] = g;
    }
    __syncthreads();
    const float gmax = s_scalar[0];

    float e = 0.f;
    if (t < L_SEQ) {
        e = __expf(x - gmax);
        s_logits[t] = e;   // numerator
    }
    float ssum = e;
    ssum += __shfl_down(ssum, 32);
    ssum += __shfl_down(ssum, 16);
    ssum += __shfl_down(ssum, 8);
    ssum += __shfl_down(ssum, 4);
    ssum += __shfl_down(ssum, 2);
    ssum += __shfl_down(ssum, 1);
    if ((t & 63) == 0) s_red[wid] = ssum;
    __syncthreads();
    if (t == 0) {
        float g = 0.f;
        #pragma unroll
        for (int i = 0; i < 8; ++i) g += s_red[i];
        s_scalar[1] = g;
    }
    __syncthreads();
    const float inv = 1.0f / s_scalar[1];

    // ---- pass 2: out[h] = sum_l score[l] * hist[l,h] ----
    float4 acc = make_float4(0.f, 0.f, 0.f, 0.f);
    #pragma unroll
    for (int i = 0; i < 12; ++i) {
        const float s = s_logits[i * 16 + lgroup] * inv;   // LDS broadcast
        acc.x = fmaf(s, r[i].x, acc.x);
        acc.y = fmaf(s, r[i].y, acc.y);
        acc.z = fmaf(s, r[i].z, acc.z);
        acc.w = fmaf(s, r[i].w, acc.w);
    }
    if (tail) {
        const float s = s_logits[192 + lgroup] * inv;
        acc.x = fmaf(s, r[12].x, acc.x);
        acc.y = fmaf(s, r[12].y, acc.y);
        acc.z = fmaf(s, r[12].z, acc.z);
        acc.w = fmaf(s, r[12].w, acc.w);
    }
    reinterpret_cast<float4*>(s_part)[lgroup * 32 + lane32] = acc;
    __syncthreads();
    if (t < H_DIM) {
        float v = 0.f;
        #pragma unroll
        for (int g = 0; g < 16; ++g) v += s_part[g * H_DIM + t];  // 2-way/bank: free
        out[(size_t)b * H_DIM + t] = v;
    }
}

extern "C" void kernel_launch(void* const* d_in, const int* in_sizes, int n_in,
                              void* d_out, int out_size, void* d_ws, size_t ws_size,
                              hipStream_t stream) {
    const float* query = (const float*)d_in[0];   // [B, 128]
    const float* hist  = (const float*)d_in[1];   // [B, 200, 128]
    const int*   lens  = (const int*)d_in[2];     // [B]
    const float* W     = (const float*)d_in[3];   // [128, 128]
    float* out = (float*)d_out;                   // [B, 128]
    float* qw  = (float*)d_ws;                    // [B, 128] scratch (4 MB)

    const int B = in_sizes[2];                    // 8192
    qw_kernel<<<dim3(B), dim3(128), 0, stream>>>(query, W, qw);
    attn_pool<<<dim3(B), dim3(512), 0, stream>>>(qw, hist, lens, out);
}